// Round 4
// baseline (206.578 us; speedup 1.0000x reference)
//
#include <hip/hip_runtime.h>
#include <hip/hip_bf16.h>

// Triplane sampling, MI355X.
// For each point (x,y,z): sample 3 planes at (gx,gy) = (y,x), (z,x), (y,z),
// bilinear, align_corners=True. out[m*32+c] = sum over planes.
//
// Pipeline:
//   1. repack triplane [3][C][512][512] f32 -> channel-last bf16 [3][512][512][C]
//   2. Morton counting-sort points into 32768 cells (zero+hist, scan, scatter)
//   3. gather in Morton order (L2-local footprints), scatter-write 128B rows
//
// ws layout: [hist 128KB][sorted 16MB][texels 50.3MB]

#define RRTP 262144   // 512*512
#define CTP  32
#define NBUCKET 32768

typedef float        f32x4 __attribute__((ext_vector_type(4)));
typedef unsigned int u32;
typedef u32          u32x4 __attribute__((ext_vector_type(4)));

// ------------- Morton key: 5 bits/axis, 15-bit key ------------------------
__device__ __forceinline__ u32 part3(u32 v) {
    return (v & 1) | ((v & 2) << 2) | ((v & 4) << 4) | ((v & 8) << 6) | ((v & 16) << 8);
}
__device__ __forceinline__ u32 morton_key(float px, float py, float pz) {
    int qx = (int)((px + 1.0f) * 16.0f);
    int qy = (int)((py + 1.0f) * 16.0f);
    int qz = (int)((pz + 1.0f) * 16.0f);
    qx = max(0, min(31, qx)); qy = max(0, min(31, qy)); qz = max(0, min(31, qz));
    return part3((u32)qx) | (part3((u32)qy) << 1) | (part3((u32)qz) << 2);
}

// ------------- Kernel: [3][C][R][R] f32 -> [3][R][R][C] bf16 --------------
__global__ __launch_bounds__(256) void tp_transpose_bf16(const float* __restrict__ in,
                                                         u32* __restrict__ out,
                                                         const int* __restrict__ oid) {
    __shared__ float tile[256][33];
    const int b     = blockIdx.x;              // 0..3071
    const int plane = b >> 10;
    const int rr0   = (b & 1023) << 8;
    const int t     = threadIdx.x;

    const float* src = in + (size_t)oid[0] * (3u * CTP * RRTP)
                          + (size_t)plane * (CTP * RRTP) + rr0 + t;
    #pragma unroll
    for (int c = 0; c < 32; ++c)
        tile[t][c] = src[(size_t)c * RRTP];
    __syncthreads();

    u32* dst = out + (size_t)plane * ((size_t)RRTP * 16) + (size_t)rr0 * 16;
    const int cp = t & 15;
    #pragma unroll
    for (int k = 0; k < 16; ++k) {
        const int r = (k << 4) + (t >> 4);
        const float f0 = tile[r][cp * 2];
        const float f1 = tile[r][cp * 2 + 1];
        const u32 lo = (u32)__bfloat16_as_ushort(__float2bfloat16(f0));
        const u32 hi = (u32)__bfloat16_as_ushort(__float2bfloat16(f1));
        dst[(size_t)r * 16 + cp] = (hi << 16) | lo;
    }
}

// ------------- Sort kernels -----------------------------------------------
__global__ __launch_bounds__(256) void tp_zero(u32* __restrict__ hist) {
    hist[blockIdx.x * 256 + threadIdx.x] = 0u;
}

__global__ __launch_bounds__(256) void tp_hist(const float* __restrict__ xyz,
                                               u32* __restrict__ hist, int Mtot) {
    const int m = blockIdx.x * 256 + threadIdx.x;
    if (m >= Mtot) return;
    const u32 k = morton_key(xyz[3 * m], xyz[3 * m + 1], xyz[3 * m + 2]);
    atomicAdd(&hist[k], 1u);
}

// single-workgroup exclusive scan of 32768 counters (in place)
__global__ __launch_bounds__(1024) void tp_scan(u32* __restrict__ hist) {
    __shared__ u32 sums[1024];
    const int t = threadIdx.x;
    u32 local[32];
    u32 s = 0;
    #pragma unroll
    for (int i = 0; i < 32; ++i) { local[i] = hist[t * 32 + i]; s += local[i]; }
    sums[t] = s;
    __syncthreads();
    for (int off = 1; off < 1024; off <<= 1) {
        const u32 v = (t >= off) ? sums[t - off] : 0u;
        __syncthreads();
        sums[t] += v;
        __syncthreads();
    }
    u32 run = (t == 0) ? 0u : sums[t - 1];
    #pragma unroll
    for (int i = 0; i < 32; ++i) { const u32 c = local[i]; hist[t * 32 + i] = run; run += c; }
}

__global__ __launch_bounds__(256) void tp_scatter(const float* __restrict__ xyz,
                                                  u32* __restrict__ off,
                                                  f32x4* __restrict__ sorted, int Mtot) {
    const int m = blockIdx.x * 256 + threadIdx.x;
    if (m >= Mtot) return;
    const float px = xyz[3 * m], py = xyz[3 * m + 1], pz = xyz[3 * m + 2];
    const u32 k = morton_key(px, py, pz);
    const u32 pos = atomicAdd(&off[k], 1u);
    f32x4 v = {px, py, pz, __uint_as_float((u32)m)};
    sorted[pos] = v;
}

// ------------- Gather: Morton-ordered, channel-last bf16 ------------------
// 4 threads per sorted point; thread handles 8 channels (4 u32 = 16B/corner).
__global__ __launch_bounds__(256) void tp_sample_sorted(const f32x4* __restrict__ sorted,
                                                        const u32* __restrict__ tp,
                                                        float* __restrict__ out,
                                                        int Mtot, int nwg) {
    // bijective XCD-chunk remap: each XCD gets a contiguous Morton range
    const int bid = blockIdx.x;
    const int qc = nwg >> 3, rc = nwg & 7;
    const int xcd = bid & 7, j = bid >> 3;
    const int wg = ((xcd < rc) ? xcd * (qc + 1) : rc * (qc + 1) + (xcd - rc) * qc) + j;

    const int tid = wg * 256 + threadIdx.x;
    const int sp = tid >> 2;
    if (sp >= Mtot) return;
    const int qu = (tid & 3) << 2;             // u32 offset within texel

    const f32x4 pt = sorted[sp];
    const float px = pt.x, py = pt.y, pz = pt.z;
    const u32 m = __float_as_uint(pt.w);

    const float gxs[3] = {py, pz, py};
    const float gys[3] = {px, px, pz};

    f32x4 alo = {0.f, 0.f, 0.f, 0.f};
    f32x4 ahi = {0.f, 0.f, 0.f, 0.f};

    #pragma unroll
    for (int p = 0; p < 3; ++p) {
        const float xf = (gxs[p] + 1.0f) * (0.5f * 511.0f);
        const float yf = (gys[p] + 1.0f) * (0.5f * 511.0f);
        const float x0f = floorf(xf), y0f = floorf(yf);
        float wx1 = xf - x0f, wy1 = yf - y0f;
        float wx0 = 1.0f - wx1, wy0 = 1.0f - wy1;

        int x0 = (int)x0f, y0 = (int)y0f;
        int x1 = x0 + 1,   y1 = y0 + 1;
        if (x1 > 511) { x1 = 511; wx1 = 0.0f; }   // zero-pad edge semantics
        if (y1 > 511) { y1 = 511; wy1 = 0.0f; }
        x0 = max(0, min(511, x0));
        y0 = max(0, min(511, y0));

        const u32* bp = tp + ((size_t)p << 22) + qu;  // p*R*R*16 + qu
        const u32x4 v00 = *(const u32x4*)(bp + (size_t)(((y0 << 9) + x0) << 4));
        const u32x4 v01 = *(const u32x4*)(bp + (size_t)(((y0 << 9) + x1) << 4));
        const u32x4 v10 = *(const u32x4*)(bp + (size_t)(((y1 << 9) + x0) << 4));
        const u32x4 v11 = *(const u32x4*)(bp + (size_t)(((y1 << 9) + x1) << 4));

        const float w00 = wy0 * wx0, w01 = wy0 * wx1;
        const float w10 = wy1 * wx0, w11 = wy1 * wx1;

        #pragma unroll
        for (int i = 0; i < 4; ++i) {
            const float l00 = __uint_as_float(v00[i] << 16), h00 = __uint_as_float(v00[i] & 0xffff0000u);
            const float l01 = __uint_as_float(v01[i] << 16), h01 = __uint_as_float(v01[i] & 0xffff0000u);
            const float l10 = __uint_as_float(v10[i] << 16), h10 = __uint_as_float(v10[i] & 0xffff0000u);
            const float l11 = __uint_as_float(v11[i] << 16), h11 = __uint_as_float(v11[i] & 0xffff0000u);
            alo[i] = fmaf(w00, l00, fmaf(w01, l01, fmaf(w10, l10, fmaf(w11, l11, alo[i]))));
            ahi[i] = fmaf(w00, h00, fmaf(w01, h01, fmaf(w10, h10, fmaf(w11, h11, ahi[i]))));
        }
    }

    float* ob = out + ((size_t)m << 5) + (qu << 1);
    f32x4 s0 = {alo[0], ahi[0], alo[1], ahi[1]};
    f32x4 s1 = {alo[2], ahi[2], alo[3], ahi[3]};
    __builtin_nontemporal_store(s0, (f32x4*)ob);
    __builtin_nontemporal_store(s1, (f32x4*)(ob + 4));
}

// ------------- Fallback: direct sample from [3][C][R][R] ------------------
__global__ __launch_bounds__(256) void tp_sample_direct(const float* __restrict__ xyz,
                                                        const float* __restrict__ tpl,
                                                        const int* __restrict__ oid,
                                                        float* __restrict__ out,
                                                        int Mtot) {
    const int tid = blockIdx.x * 256 + threadIdx.x;
    const int m = tid >> 5;
    if (m >= Mtot) return;
    const int c = tid & 31;
    const float px = xyz[m * 3 + 0], py = xyz[m * 3 + 1], pz = xyz[m * 3 + 2];
    const float gxs[3] = {py, pz, py};
    const float gys[3] = {px, px, pz};
    const float* base = tpl + (size_t)oid[0] * (3u * CTP * RRTP);
    float acc = 0.f;
    #pragma unroll
    for (int p = 0; p < 3; ++p) {
        const float xf = (gxs[p] + 1.0f) * (0.5f * 511.0f);
        const float yf = (gys[p] + 1.0f) * (0.5f * 511.0f);
        const float x0f = floorf(xf), y0f = floorf(yf);
        float wx1 = xf - x0f, wy1 = yf - y0f;
        float wx0 = 1.0f - wx1, wy0 = 1.0f - wy1;
        int x0 = (int)x0f, y0 = (int)y0f;
        int x1 = x0 + 1,   y1 = y0 + 1;
        if (x1 > 511) { x1 = 511; wx1 = 0.0f; }
        if (y1 > 511) { y1 = 511; wy1 = 0.0f; }
        x0 = max(0, min(511, x0));
        y0 = max(0, min(511, y0));
        const float* img = base + ((size_t)p * CTP + c) * RRTP;
        acc += wy0 * (wx0 * img[(y0 << 9) + x0] + wx1 * img[(y0 << 9) + x1])
             + wy1 * (wx0 * img[(y1 << 9) + x0] + wx1 * img[(y1 << 9) + x1]);
    }
    out[((size_t)m << 5) + c] = acc;
}

extern "C" void kernel_launch(void* const* d_in, const int* in_sizes, int n_in,
                              void* d_out, int out_size, void* d_ws, size_t ws_size,
                              hipStream_t stream) {
    const float* xyz      = (const float*)d_in[0];
    const float* triplane = (const float*)d_in[1];
    const int*   oid      = (const int*)d_in[2];
    float*       out      = (float*)d_out;
    const int Mtot = in_sizes[0] / 3;          // 1,000,000

    const size_t hist_b   = (size_t)NBUCKET * 4;                 // 128 KB
    const size_t sorted_b = (size_t)Mtot * 16;                   // 16 MB
    const size_t texel_b  = (size_t)3 * RRTP * 16 * 4;           // 50.3 MB
    const size_t ws_needed = hist_b + sorted_b + texel_b;

    if (ws_size >= ws_needed) {
        u32*   hist   = (u32*)d_ws;
        f32x4* sorted = (f32x4*)((char*)d_ws + hist_b);
        u32*   texels = (u32*)((char*)d_ws + hist_b + sorted_b);

        const int nbl_pts = (Mtot + 255) / 256;
        tp_transpose_bf16<<<3072, 256, 0, stream>>>(triplane, texels, oid);
        tp_zero<<<NBUCKET / 256, 256, 0, stream>>>(hist);
        tp_hist<<<nbl_pts, 256, 0, stream>>>(xyz, hist, Mtot);
        tp_scan<<<1, 1024, 0, stream>>>(hist);
        tp_scatter<<<nbl_pts, 256, 0, stream>>>(xyz, hist, sorted, Mtot);

        const int nwg = (Mtot * 4 + 255) / 256;
        tp_sample_sorted<<<nwg, 256, 0, stream>>>(sorted, texels, out, Mtot, nwg);
    } else {
        tp_sample_direct<<<(Mtot * 32 + 255) / 256, 256, 0, stream>>>(xyz, triplane, oid, out, Mtot);
    }
}

// Round 5
// 136.340 us; speedup vs baseline: 1.5152x; 1.5152x over previous
//
#include <hip/hip_runtime.h>
#include <hip/hip_bf16.h>

// Triplane sampling, MI355X.
// For each point (x,y,z): sample 3 planes at (gx,gy) = (y,x), (z,x), (y,z),
// bilinear, align_corners=True. out[m*32+c] = sum over planes.
//
// Pipeline:
//   1. repack triplane [3][C][512][512] f32 -> channel-last bf16 [3][512][512][C]
//   2. deterministic counting sort of points into 512 Morton cells:
//        A: per-block (4096 pts) LDS histogram -> hist[block][512]
//        B: single-WG scan -> per-block exclusive offsets + bucket bases
//        C: re-key, LDS-rank, LDS-reorder, coalesced run writes (NO global atomics)
//   3. gather in Morton order (L2-local footprints), scatter-write 128B out rows
//
// ws layout: [hist 512KB][bucket_base @512KB][sorted @576KB 16MB][texels 50.3MB]

#define RRTP 262144   // 512*512
#define CTP  32
#define NB   512      // Morton buckets (3 bits/axis)
#define SORT_P 4096   // points per sort block

typedef float        f32x4 __attribute__((ext_vector_type(4)));
typedef unsigned int u32;
typedef u32          u32x4 __attribute__((ext_vector_type(4)));

// ------------- Morton key: 3 bits/axis, 9-bit key --------------------------
__device__ __forceinline__ u32 part3b(u32 v) {
    return (v & 1) | ((v & 2) << 2) | ((v & 4) << 4);
}
__device__ __forceinline__ u32 morton9(float px, float py, float pz) {
    int qx = max(0, min(7, (int)((px + 1.0f) * 4.0f)));
    int qy = max(0, min(7, (int)((py + 1.0f) * 4.0f)));
    int qz = max(0, min(7, (int)((pz + 1.0f) * 4.0f)));
    return part3b((u32)qx) | (part3b((u32)qy) << 1) | (part3b((u32)qz) << 2);
}

// ------------- Kernel: [3][C][R][R] f32 -> [3][R][R][C] bf16 --------------
__global__ __launch_bounds__(256) void tp_transpose_bf16(const float* __restrict__ in,
                                                         u32* __restrict__ out,
                                                         const int* __restrict__ oid) {
    __shared__ float tile[256][33];
    const int b     = blockIdx.x;              // 0..3071
    const int plane = b >> 10;
    const int rr0   = (b & 1023) << 8;
    const int t     = threadIdx.x;

    const float* src = in + (size_t)oid[0] * (3u * CTP * RRTP)
                          + (size_t)plane * (CTP * RRTP) + rr0 + t;
    #pragma unroll
    for (int c = 0; c < 32; ++c)
        tile[t][c] = src[(size_t)c * RRTP];
    __syncthreads();

    u32* dst = out + (size_t)plane * ((size_t)RRTP * 16) + (size_t)rr0 * 16;
    const int cp = t & 15;
    #pragma unroll
    for (int k = 0; k < 16; ++k) {
        const int r = (k << 4) + (t >> 4);
        const float f0 = tile[r][cp * 2];
        const float f1 = tile[r][cp * 2 + 1];
        const u32 lo = (u32)__bfloat16_as_ushort(__float2bfloat16(f0));
        const u32 hi = (u32)__bfloat16_as_ushort(__float2bfloat16(f1));
        dst[(size_t)r * 16 + cp] = (hi << 16) | lo;
    }
}

// ------------- Sort A: per-block histogram (LDS atomics only) -------------
__global__ __launch_bounds__(256) void tp_hist_blk(const float* __restrict__ xyz,
                                                   u32* __restrict__ hist, int Mtot) {
    __shared__ u32 cnt[NB];
    const int t = threadIdx.x, b = blockIdx.x;
    cnt[t] = 0u; cnt[t + 256] = 0u;
    __syncthreads();
    const int base_m = b * SORT_P;
    #pragma unroll
    for (int i = 0; i < 16; ++i) {
        const int m = base_m + i * 256 + t;
        if (m < Mtot) {
            const u32 k = morton9(xyz[3 * m], xyz[3 * m + 1], xyz[3 * m + 2]);
            atomicAdd(&cnt[k], 1u);
        }
    }
    __syncthreads();
    hist[b * NB + t] = cnt[t];
    hist[b * NB + t + 256] = cnt[t + 256];
}

// ------------- Sort B: scan -> per-block exclusive offsets + bucket bases --
__global__ __launch_bounds__(512) void tp_scanB(u32* __restrict__ hist,
                                                u32* __restrict__ bucket_base, int nblk) {
    const int k = threadIdx.x;   // 0..511, one bucket per thread
    u32 run = 0;
    #pragma unroll 8
    for (int b = 0; b < nblk; ++b) {
        const u32 v = hist[b * NB + k];
        hist[b * NB + k] = run;            // exclusive partial along blocks
        run += v;
    }
    // exclusive scan of totals across buckets
    __shared__ u32 sA[NB], sB[NB];
    sA[k] = run;
    int par = 0;
    for (int off = 1; off < NB; off <<= 1) {
        __syncthreads();
        u32* src = par ? sB : sA;
        u32* dst = par ? sA : sB;
        dst[k] = src[k] + ((k >= off) ? src[k - off] : 0u);
        par ^= 1;
    }
    __syncthreads();
    const u32 incl = (par ? sB : sA)[k];
    bucket_base[k] = incl - run;
}

// ------------- Sort C: LDS rank + reorder, coalesced scatter ---------------
__global__ __launch_bounds__(256) void tp_scatter_blk(const float* __restrict__ xyz,
                                                      const u32* __restrict__ hist,
                                                      const u32* __restrict__ bucket_base,
                                                      f32x4* __restrict__ sorted, int Mtot) {
    __shared__ u32 goff[NB];                 // bucket_base + blockoff, later -= lbase
    __shared__ u32 sA[NB], sB[NB];           // counts / scan ping-pong / lbase
    __shared__ f32x4 rec[SORT_P];            // 64 KB
    __shared__ unsigned short lkey[SORT_P];  // 8 KB
    const int t = threadIdx.x, b = blockIdx.x;
    const int base_m = b * SORT_P;

    sA[t] = 0u; sA[t + 256] = 0u;
    goff[t]       = bucket_base[t]       + hist[b * NB + t];
    goff[t + 256] = bucket_base[t + 256] + hist[b * NB + t + 256];
    __syncthreads();

    float xs[16], ys[16], zs[16]; u32 ks[16], rs[16];
    #pragma unroll
    for (int i = 0; i < 16; ++i) {
        const int m = base_m + i * 256 + t;
        const bool v = (m < Mtot);
        float px = 0.f, py = 0.f, pz = 0.f;
        if (v) { px = xyz[3 * m]; py = xyz[3 * m + 1]; pz = xyz[3 * m + 2]; }
        const u32 key = morton9(px, py, pz);
        xs[i] = px; ys[i] = py; zs[i] = pz;
        ks[i] = v ? key : 0xffffffffu;
        rs[i] = v ? atomicAdd(&sA[key], 1u) : 0u;
    }
    __syncthreads();

    const u32 c0 = sA[t], c1 = sA[t + 256];
    int par = 0;
    for (int off = 1; off < NB; off <<= 1) {     // inclusive scan, ping-pong
        u32* src = par ? sB : sA;
        u32* dst = par ? sA : sB;
        const u32 a0 = src[t]       + ((t >= off)       ? src[t - off]       : 0u);
        const u32 a1 = src[t + 256] + ((t + 256 >= off) ? src[t + 256 - off] : 0u);
        dst[t] = a0; dst[t + 256] = a1;
        par ^= 1;
        __syncthreads();
    }
    u32* incl = par ? sB : sA;                   // par==1 -> sB after 9 iters
    const u32 lb0 = incl[t] - c0, lb1 = incl[t + 256] - c1;
    __syncthreads();
    sA[t] = lb0; sA[t + 256] = lb1;              // sA := lbase
    goff[t] -= lb0; goff[t + 256] -= lb1;        // goff := global start - lbase
    __syncthreads();

    #pragma unroll
    for (int i = 0; i < 16; ++i) {               // LDS reorder
        if (ks[i] != 0xffffffffu) {
            const u32 pos = sA[ks[i]] + rs[i];
            f32x4 r = {xs[i], ys[i], zs[i],
                       __uint_as_float((u32)(base_m + i * 256 + t))};
            rec[pos] = r;
            lkey[pos] = (unsigned short)ks[i];
        }
    }
    __syncthreads();

    const int nv = min(SORT_P, Mtot - base_m);
    #pragma unroll
    for (int i = 0; i < 16; ++i) {               // coalesced run writes
        const int s = i * 256 + t;
        if (s < nv) {
            const u32 k2 = lkey[s];
            sorted[goff[k2] + s] = rec[s];
        }
    }
}

// ------------- Gather: Morton-ordered, channel-last bf16 ------------------
__global__ __launch_bounds__(256) void tp_sample_sorted(const f32x4* __restrict__ sorted,
                                                        const u32* __restrict__ tp,
                                                        float* __restrict__ out,
                                                        int Mtot, int nwg) {
    // bijective XCD-chunk remap: each XCD gets a contiguous Morton range
    const int bid = blockIdx.x;
    const int qc = nwg >> 3, rc = nwg & 7;
    const int xcd = bid & 7, j = bid >> 3;
    const int wg = ((xcd < rc) ? xcd * (qc + 1) : rc * (qc + 1) + (xcd - rc) * qc) + j;

    const int tid = wg * 256 + threadIdx.x;
    const int sp = tid >> 2;
    if (sp >= Mtot) return;
    const int qu = (tid & 3) << 2;             // u32 offset within texel

    const f32x4 pt = sorted[sp];
    const float px = pt.x, py = pt.y, pz = pt.z;
    const u32 m = __float_as_uint(pt.w);

    const float gxs[3] = {py, pz, py};
    const float gys[3] = {px, px, pz};

    f32x4 alo = {0.f, 0.f, 0.f, 0.f};
    f32x4 ahi = {0.f, 0.f, 0.f, 0.f};

    #pragma unroll
    for (int p = 0; p < 3; ++p) {
        const float xf = (gxs[p] + 1.0f) * (0.5f * 511.0f);
        const float yf = (gys[p] + 1.0f) * (0.5f * 511.0f);
        const float x0f = floorf(xf), y0f = floorf(yf);
        float wx1 = xf - x0f, wy1 = yf - y0f;
        float wx0 = 1.0f - wx1, wy0 = 1.0f - wy1;

        int x0 = (int)x0f, y0 = (int)y0f;
        int x1 = x0 + 1,   y1 = y0 + 1;
        if (x1 > 511) { x1 = 511; wx1 = 0.0f; }   // zero-pad edge semantics
        if (y1 > 511) { y1 = 511; wy1 = 0.0f; }
        x0 = max(0, min(511, x0));
        y0 = max(0, min(511, y0));

        const u32* bp = tp + ((size_t)p << 22) + qu;  // p*R*R*16 + qu
        const u32x4 v00 = *(const u32x4*)(bp + (size_t)(((y0 << 9) + x0) << 4));
        const u32x4 v01 = *(const u32x4*)(bp + (size_t)(((y0 << 9) + x1) << 4));
        const u32x4 v10 = *(const u32x4*)(bp + (size_t)(((y1 << 9) + x0) << 4));
        const u32x4 v11 = *(const u32x4*)(bp + (size_t)(((y1 << 9) + x1) << 4));

        const float w00 = wy0 * wx0, w01 = wy0 * wx1;
        const float w10 = wy1 * wx0, w11 = wy1 * wx1;

        #pragma unroll
        for (int i = 0; i < 4; ++i) {
            const float l00 = __uint_as_float(v00[i] << 16), h00 = __uint_as_float(v00[i] & 0xffff0000u);
            const float l01 = __uint_as_float(v01[i] << 16), h01 = __uint_as_float(v01[i] & 0xffff0000u);
            const float l10 = __uint_as_float(v10[i] << 16), h10 = __uint_as_float(v10[i] & 0xffff0000u);
            const float l11 = __uint_as_float(v11[i] << 16), h11 = __uint_as_float(v11[i] & 0xffff0000u);
            alo[i] = fmaf(w00, l00, fmaf(w01, l01, fmaf(w10, l10, fmaf(w11, l11, alo[i]))));
            ahi[i] = fmaf(w00, h00, fmaf(w01, h01, fmaf(w10, h10, fmaf(w11, h11, ahi[i]))));
        }
    }

    float* ob = out + ((size_t)m << 5) + (qu << 1);
    f32x4 s0 = {alo[0], ahi[0], alo[1], ahi[1]};
    f32x4 s1 = {alo[2], ahi[2], alo[3], ahi[3]};
    __builtin_nontemporal_store(s0, (f32x4*)ob);
    __builtin_nontemporal_store(s1, (f32x4*)(ob + 4));
}

// ------------- Fallback: direct sample from [3][C][R][R] ------------------
__global__ __launch_bounds__(256) void tp_sample_direct(const float* __restrict__ xyz,
                                                        const float* __restrict__ tpl,
                                                        const int* __restrict__ oid,
                                                        float* __restrict__ out,
                                                        int Mtot) {
    const int tid = blockIdx.x * 256 + threadIdx.x;
    const int m = tid >> 5;
    if (m >= Mtot) return;
    const int c = tid & 31;
    const float px = xyz[m * 3 + 0], py = xyz[m * 3 + 1], pz = xyz[m * 3 + 2];
    const float gxs[3] = {py, pz, py};
    const float gys[3] = {px, px, pz};
    const float* base = tpl + (size_t)oid[0] * (3u * CTP * RRTP);
    float acc = 0.f;
    #pragma unroll
    for (int p = 0; p < 3; ++p) {
        const float xf = (gxs[p] + 1.0f) * (0.5f * 511.0f);
        const float yf = (gys[p] + 1.0f) * (0.5f * 511.0f);
        const float x0f = floorf(xf), y0f = floorf(yf);
        float wx1 = xf - x0f, wy1 = yf - y0f;
        float wx0 = 1.0f - wx1, wy0 = 1.0f - wy1;
        int x0 = (int)x0f, y0 = (int)y0f;
        int x1 = x0 + 1,   y1 = y0 + 1;
        if (x1 > 511) { x1 = 511; wx1 = 0.0f; }
        if (y1 > 511) { y1 = 511; wy1 = 0.0f; }
        x0 = max(0, min(511, x0));
        y0 = max(0, min(511, y0));
        const float* img = base + ((size_t)p * CTP + c) * RRTP;
        acc += wy0 * (wx0 * img[(y0 << 9) + x0] + wx1 * img[(y0 << 9) + x1])
             + wy1 * (wx0 * img[(y1 << 9) + x0] + wx1 * img[(y1 << 9) + x1]);
    }
    out[((size_t)m << 5) + c] = acc;
}

extern "C" void kernel_launch(void* const* d_in, const int* in_sizes, int n_in,
                              void* d_out, int out_size, void* d_ws, size_t ws_size,
                              hipStream_t stream) {
    const float* xyz      = (const float*)d_in[0];
    const float* triplane = (const float*)d_in[1];
    const int*   oid      = (const int*)d_in[2];
    float*       out      = (float*)d_out;
    const int Mtot = in_sizes[0] / 3;          // 1,000,000
    const int nblk = (Mtot + SORT_P - 1) / SORT_P;   // 245

    const size_t hist_b   = 512 * 1024;                          // >= nblk*NB*4
    const size_t bb_off   = hist_b;                              // 2 KB used
    const size_t sorted_off = hist_b + 64 * 1024;                // 16B aligned
    const size_t sorted_b = (size_t)Mtot * 16;                   // 16 MB
    const size_t texel_off = sorted_off + sorted_b;
    const size_t texel_b  = (size_t)3 * RRTP * 16 * 4;           // 50.3 MB
    const size_t ws_needed = texel_off + texel_b;

    if (ws_size >= ws_needed && (size_t)nblk * NB * 4 <= hist_b) {
        u32*   hist   = (u32*)d_ws;
        u32*   bbase  = (u32*)((char*)d_ws + bb_off);
        f32x4* sorted = (f32x4*)((char*)d_ws + sorted_off);
        u32*   texels = (u32*)((char*)d_ws + texel_off);

        tp_transpose_bf16<<<3072, 256, 0, stream>>>(triplane, texels, oid);
        tp_hist_blk<<<nblk, 256, 0, stream>>>(xyz, hist, Mtot);
        tp_scanB<<<1, 512, 0, stream>>>(hist, bbase, nblk);
        tp_scatter_blk<<<nblk, 256, 0, stream>>>(xyz, hist, bbase, sorted, Mtot);

        const int nwg = (Mtot * 4 + 255) / 256;
        tp_sample_sorted<<<nwg, 256, 0, stream>>>(sorted, texels, out, Mtot, nwg);
    } else {
        tp_sample_direct<<<(Mtot * 32 + 255) / 256, 256, 0, stream>>>(xyz, triplane, oid, out, Mtot);
    }
}

// Round 7
// 132.489 us; speedup vs baseline: 1.5592x; 1.0291x over previous
//
#include <hip/hip_runtime.h>
#include <hip/hip_bf16.h>

// Triplane sampling, MI355X.
// For each point (x,y,z): sample 3 planes at (gx,gy) = (y,x), (z,x), (y,z),
// bilinear, align_corners=True. out[m*32+c] = sum over planes.
//
// Pipeline:
//   K1 fused: [3][C][512][512] f32 -> channel-last bf16 [3][512][512][C]
//             (blocks 0..3071)  ||  per-block point histogram (blocks 3072..)
//   K2 single-WG scan -> per-block exclusive offsets + bucket bases
//   K3 LDS-rank counting-sort scatter (no global atomics, coalesced runs)
//   K4 gather in Morton order (L2-local), scatter-write 128B out rows
//
// ws layout: [hist 512KB][bucket_base @512KB][sorted @576KB 16MB][texels 50.3MB]

#define RRTP 262144   // 512*512
#define CTP  32
#define NB   512      // Morton buckets (3 bits/axis)
#define SORT_P 4096   // points per sort block
#define TPBLK 3072    // transpose blocks in fused kernel
#define PLANE_B (RRTP * 64)   // bytes per channel-last bf16 plane (16.78 MB)

typedef float        f32x4 __attribute__((ext_vector_type(4)));
typedef unsigned int u32;
typedef u32          u32x4 __attribute__((ext_vector_type(4)));

// ------------- Morton key: 3 bits/axis, 9-bit key --------------------------
__device__ __forceinline__ u32 part3b(u32 v) {
    return (v & 1) | ((v & 2) << 2) | ((v & 4) << 4);
}
__device__ __forceinline__ u32 morton9(float px, float py, float pz) {
    int qx = max(0, min(7, (int)((px + 1.0f) * 4.0f)));
    int qy = max(0, min(7, (int)((py + 1.0f) * 4.0f)));
    int qz = max(0, min(7, (int)((pz + 1.0f) * 4.0f)));
    return part3b((u32)qx) | (part3b((u32)qy) << 1) | (part3b((u32)qz) << 2);
}

// ------------- K1: fused transpose+quantize || histogram -------------------
__global__ __launch_bounds__(256) void tp_fused(const float* __restrict__ in,
                                                u32* __restrict__ texels,
                                                const float* __restrict__ xyz,
                                                u32* __restrict__ hist,
                                                const int* __restrict__ oid, int Mtot) {
    __shared__ float tile[256][33];            // hist path aliases first 2KB
    const int t = threadIdx.x;

    if (blockIdx.x < TPBLK) {
        const int b     = blockIdx.x;
        const int plane = b >> 10;
        const int rr0   = (b & 1023) << 8;

        const float* src = in + (size_t)oid[0] * (3u * CTP * RRTP)
                              + (size_t)plane * (CTP * RRTP) + rr0 + t;
        #pragma unroll
        for (int c = 0; c < 32; ++c)
            tile[t][c] = src[(size_t)c * RRTP];
        __syncthreads();

        u32* dst = texels + (size_t)plane * ((size_t)RRTP * 16) + (size_t)rr0 * 16;
        const int cp = t & 15;
        #pragma unroll
        for (int k = 0; k < 16; ++k) {
            const int r = (k << 4) + (t >> 4);
            const float f0 = tile[r][cp * 2];
            const float f1 = tile[r][cp * 2 + 1];
            const u32 lo = (u32)__bfloat16_as_ushort(__float2bfloat16(f0));
            const u32 hi = (u32)__bfloat16_as_ushort(__float2bfloat16(f1));
            dst[(size_t)r * 16 + cp] = (hi << 16) | lo;
        }
    } else {
        u32* cnt = (u32*)&tile[0][0];
        const int b = blockIdx.x - TPBLK;
        cnt[t] = 0u; cnt[t + 256] = 0u;
        __syncthreads();
        const int base_m = b * SORT_P;
        #pragma unroll
        for (int i = 0; i < 16; ++i) {
            const int m = base_m + i * 256 + t;
            if (m < Mtot) {
                const u32 k = morton9(xyz[3 * m], xyz[3 * m + 1], xyz[3 * m + 2]);
                atomicAdd(&cnt[k], 1u);
            }
        }
        __syncthreads();
        hist[b * NB + t] = cnt[t];
        hist[b * NB + t + 256] = cnt[t + 256];
    }
}

// ------------- K2: scan -> per-block exclusive offsets + bucket bases ------
__global__ __launch_bounds__(512) void tp_scanB(u32* __restrict__ hist,
                                                u32* __restrict__ bucket_base, int nblk) {
    const int k = threadIdx.x;   // 0..511, one bucket per thread
    u32 run = 0;
    #pragma unroll 8
    for (int b = 0; b < nblk; ++b) {
        const u32 v = hist[b * NB + k];
        hist[b * NB + k] = run;            // exclusive partial along blocks
        run += v;
    }
    __shared__ u32 sA[NB], sB[NB];
    sA[k] = run;
    int par = 0;
    for (int off = 1; off < NB; off <<= 1) {
        __syncthreads();
        u32* src = par ? sB : sA;
        u32* dst = par ? sA : sB;
        dst[k] = src[k] + ((k >= off) ? src[k - off] : 0u);
        par ^= 1;
    }
    __syncthreads();
    const u32 incl = (par ? sB : sA)[k];
    bucket_base[k] = incl - run;
}

// ------------- K3: LDS rank + reorder, coalesced scatter -------------------
__global__ __launch_bounds__(256) void tp_scatter_blk(const float* __restrict__ xyz,
                                                      const u32* __restrict__ hist,
                                                      const u32* __restrict__ bucket_base,
                                                      f32x4* __restrict__ sorted, int Mtot) {
    __shared__ u32 goff[NB];
    __shared__ u32 sA[NB], sB[NB];
    __shared__ f32x4 rec[SORT_P];            // 64 KB
    __shared__ unsigned short lkey[SORT_P];  // 8 KB
    const int t = threadIdx.x, b = blockIdx.x;
    const int base_m = b * SORT_P;

    sA[t] = 0u; sA[t + 256] = 0u;
    goff[t]       = bucket_base[t]       + hist[b * NB + t];
    goff[t + 256] = bucket_base[t + 256] + hist[b * NB + t + 256];
    __syncthreads();

    float xs[16], ys[16], zs[16]; u32 ks[16], rs[16];
    #pragma unroll
    for (int i = 0; i < 16; ++i) {
        const int m = base_m + i * 256 + t;
        const bool v = (m < Mtot);
        float px = 0.f, py = 0.f, pz = 0.f;
        if (v) { px = xyz[3 * m]; py = xyz[3 * m + 1]; pz = xyz[3 * m + 2]; }
        const u32 key = morton9(px, py, pz);
        xs[i] = px; ys[i] = py; zs[i] = pz;
        ks[i] = v ? key : 0xffffffffu;
        rs[i] = v ? atomicAdd(&sA[key], 1u) : 0u;
    }
    __syncthreads();

    const u32 c0 = sA[t], c1 = sA[t + 256];
    int par = 0;
    for (int off = 1; off < NB; off <<= 1) {     // inclusive scan, ping-pong
        u32* src = par ? sB : sA;
        u32* dst = par ? sA : sB;
        const u32 a0 = src[t]       + ((t >= off)       ? src[t - off]       : 0u);
        const u32 a1 = src[t + 256] + ((t + 256 >= off) ? src[t + 256 - off] : 0u);
        dst[t] = a0; dst[t + 256] = a1;
        par ^= 1;
        __syncthreads();
    }
    u32* incl = par ? sB : sA;
    const u32 lb0 = incl[t] - c0, lb1 = incl[t + 256] - c1;
    __syncthreads();
    sA[t] = lb0; sA[t + 256] = lb1;              // sA := lbase
    goff[t] -= lb0; goff[t + 256] -= lb1;        // goff := global start - lbase
    __syncthreads();

    #pragma unroll
    for (int i = 0; i < 16; ++i) {               // LDS reorder
        if (ks[i] != 0xffffffffu) {
            const u32 pos = sA[ks[i]] + rs[i];
            f32x4 r = {xs[i], ys[i], zs[i],
                       __uint_as_float((u32)(base_m + i * 256 + t))};
            rec[pos] = r;
            lkey[pos] = (unsigned short)ks[i];
        }
    }
    __syncthreads();

    const int nv = min(SORT_P, Mtot - base_m);
    #pragma unroll
    for (int i = 0; i < 16; ++i) {               // coalesced run writes
        const int s = i * 256 + t;
        if (s < nv) {
            const u32 k2 = lkey[s];
            sorted[goff[k2] + s] = rec[s];
        }
    }
}

// ------------- K4: gather, Morton-ordered, channel-last bf16 ---------------
// 4 threads/point. All texel loads: uniform SGPR plane base + u32 voffset.
__global__ __launch_bounds__(256) void tp_sample_sorted(const f32x4* __restrict__ sorted,
                                                        const u32* __restrict__ tp,
                                                        float* __restrict__ out,
                                                        int Mtot, int nwg) {
    // bijective XCD-chunk remap: each XCD gets a contiguous Morton range
    const int bid = blockIdx.x;
    const int qc = nwg >> 3, rc = nwg & 7;
    const int xcd = bid & 7, j = bid >> 3;
    const int wg = ((xcd < rc) ? xcd * (qc + 1) : rc * (qc + 1) + (xcd - rc) * qc) + j;

    const int tid = wg * 256 + threadIdx.x;
    const int sp = tid >> 2;
    if (sp >= Mtot) return;
    const u32 oq = (u32)((tid & 3) << 4);      // byte offset of 4-u32 slice

    const f32x4 pt = sorted[sp];
    const float px = pt.x, py = pt.y, pz = pt.z;
    const u32 m = __float_as_uint(pt.w);

    const float gxs[3] = {py, pz, py};
    const float gys[3] = {px, px, pz};

    f32x4 alo = {0.f, 0.f, 0.f, 0.f};
    f32x4 ahi = {0.f, 0.f, 0.f, 0.f};

    const char* tpc = (const char*)tp;

    #pragma unroll
    for (int p = 0; p < 3; ++p) {
        const float xf = (gxs[p] + 1.0f) * (0.5f * 511.0f);
        const float yf = (gys[p] + 1.0f) * (0.5f * 511.0f);
        const float x0f = floorf(xf), y0f = floorf(yf);
        float wx1 = xf - x0f, wy1 = yf - y0f;
        float wx0 = 1.0f - wx1, wy0 = 1.0f - wy1;

        int x0 = (int)x0f, y0 = (int)y0f;
        int x1 = x0 + 1,   y1 = y0 + 1;
        if (x1 > 511) { x1 = 511; wx1 = 0.0f; }   // zero-pad edge semantics
        if (y1 > 511) { y1 = 511; wy1 = 0.0f; }
        x0 = max(0, min(511, x0));
        y0 = max(0, min(511, y0));

        // u32 byte offsets: texel (y,x) at ((y<<9)+x)*64 within plane
        const u32 ry0 = ((u32)y0 << 15), ry1 = ((u32)y1 << 15);
        const u32 cx0 = ((u32)x0 << 6)  + oq, cx1 = ((u32)x1 << 6) + oq;
        const char* base_p = tpc + (size_t)p * PLANE_B;   // uniform per iter

        const u32x4 v00 = *(const u32x4*)(base_p + (ry0 + cx0));
        const u32x4 v01 = *(const u32x4*)(base_p + (ry0 + cx1));
        const u32x4 v10 = *(const u32x4*)(base_p + (ry1 + cx0));
        const u32x4 v11 = *(const u32x4*)(base_p + (ry1 + cx1));

        const float w00 = wy0 * wx0, w01 = wy0 * wx1;
        const float w10 = wy1 * wx0, w11 = wy1 * wx1;

        #pragma unroll
        for (int i = 0; i < 4; ++i) {
            const float l00 = __uint_as_float(v00[i] << 16), h00 = __uint_as_float(v00[i] & 0xffff0000u);
            const float l01 = __uint_as_float(v01[i] << 16), h01 = __uint_as_float(v01[i] & 0xffff0000u);
            const float l10 = __uint_as_float(v10[i] << 16), h10 = __uint_as_float(v10[i] & 0xffff0000u);
            const float l11 = __uint_as_float(v11[i] << 16), h11 = __uint_as_float(v11[i] & 0xffff0000u);
            alo[i] = fmaf(w00, l00, fmaf(w01, l01, fmaf(w10, l10, fmaf(w11, l11, alo[i]))));
            ahi[i] = fmaf(w00, h00, fmaf(w01, h01, fmaf(w10, h10, fmaf(w11, h11, ahi[i]))));
        }
    }

    // oq bytes = (tid&3)*16B = 4 u32 = 8 channels -> float offset oq>>1
    float* ob = out + ((size_t)m << 5) + (size_t)(oq >> 1);
    f32x4 s0 = {alo[0], ahi[0], alo[1], ahi[1]};
    f32x4 s1 = {alo[2], ahi[2], alo[3], ahi[3]};
    __builtin_nontemporal_store(s0, (f32x4*)ob);
    __builtin_nontemporal_store(s1, (f32x4*)(ob + 4));
}

// ------------- Fallback: direct sample from [3][C][R][R] -------------------
__global__ __launch_bounds__(256) void tp_sample_direct(const float* __restrict__ xyz,
                                                        const float* __restrict__ tpl,
                                                        const int* __restrict__ oid,
                                                        float* __restrict__ out,
                                                        int Mtot) {
    const int tid = blockIdx.x * 256 + threadIdx.x;
    const int m = tid >> 5;
    if (m >= Mtot) return;
    const int c = tid & 31;
    const float px = xyz[m * 3 + 0], py = xyz[m * 3 + 1], pz = xyz[m * 3 + 2];
    const float gxs[3] = {py, pz, py};
    const float gys[3] = {px, px, pz};
    const float* base = tpl + (size_t)oid[0] * (3u * CTP * RRTP);
    float acc = 0.f;
    #pragma unroll
    for (int p = 0; p < 3; ++p) {
        const float xf = (gxs[p] + 1.0f) * (0.5f * 511.0f);
        const float yf = (gys[p] + 1.0f) * (0.5f * 511.0f);
        const float x0f = floorf(xf), y0f = floorf(yf);
        float wx1 = xf - x0f, wy1 = yf - y0f;
        float wx0 = 1.0f - wx1, wy0 = 1.0f - wy1;
        int x0 = (int)x0f, y0 = (int)y0f;
        int x1 = x0 + 1,   y1 = y0 + 1;
        if (x1 > 511) { x1 = 511; wx1 = 0.0f; }
        if (y1 > 511) { y1 = 511; wy1 = 0.0f; }
        x0 = max(0, min(511, x0));
        y0 = max(0, min(511, y0));
        const float* img = base + ((size_t)p * CTP + c) * RRTP;
        acc += wy0 * (wx0 * img[(y0 << 9) + x0] + wx1 * img[(y0 << 9) + x1])
             + wy1 * (wx0 * img[(y1 << 9) + x0] + wx1 * img[(y1 << 9) + x1]);
    }
    out[((size_t)m << 5) + c] = acc;
}

extern "C" void kernel_launch(void* const* d_in, const int* in_sizes, int n_in,
                              void* d_out, int out_size, void* d_ws, size_t ws_size,
                              hipStream_t stream) {
    const float* xyz      = (const float*)d_in[0];
    const float* triplane = (const float*)d_in[1];
    const int*   oid      = (const int*)d_in[2];
    float*       out      = (float*)d_out;
    const int Mtot = in_sizes[0] / 3;          // 1,000,000
    const int nblk = (Mtot + SORT_P - 1) / SORT_P;   // 245

    const size_t hist_b   = 512 * 1024;                          // >= nblk*NB*4
    const size_t bb_off   = hist_b;                              // 2 KB used
    const size_t sorted_off = hist_b + 64 * 1024;                // 16B aligned
    const size_t sorted_b = (size_t)Mtot * 16;                   // 16 MB
    const size_t texel_off = sorted_off + sorted_b;
    const size_t texel_b  = (size_t)3 * RRTP * 16 * 4;           // 50.3 MB
    const size_t ws_needed = texel_off + texel_b;

    if (ws_size >= ws_needed && (size_t)nblk * NB * 4 <= hist_b) {
        u32*   hist   = (u32*)d_ws;
        u32*   bbase  = (u32*)((char*)d_ws + bb_off);
        f32x4* sorted = (f32x4*)((char*)d_ws + sorted_off);
        u32*   texels = (u32*)((char*)d_ws + texel_off);

        tp_fused<<<TPBLK + nblk, 256, 0, stream>>>(triplane, texels, xyz, hist, oid, Mtot);
        tp_scanB<<<1, 512, 0, stream>>>(hist, bbase, nblk);
        tp_scatter_blk<<<nblk, 256, 0, stream>>>(xyz, hist, bbase, sorted, Mtot);

        const int nwg = (Mtot * 4 + 255) / 256;
        tp_sample_sorted<<<nwg, 256, 0, stream>>>(sorted, texels, out, Mtot, nwg);
    } else {
        tp_sample_direct<<<(Mtot * 32 + 255) / 256, 256, 0, stream>>>(xyz, triplane, oid, out, Mtot);
    }
}